// Round 13
// baseline (151.744 us; speedup 1.0000x reference)
//
#include <hip/hip_runtime.h>
#include <hip/hip_bf16.h>
#include <stdint.h>

#define NB 4096
#define NS 64
#define ND 512
#define EPSV 1e-8f

typedef float f32x4 __attribute__((ext_vector_type(4)));
typedef short bf16x8 __attribute__((ext_vector_type(8)));

__device__ __forceinline__ short f2bf(float f) {
    union { float f; unsigned u; } v; v.f = f;
    unsigned r = v.u + 0x7fffu + ((v.u >> 16) & 1u);
    return (short)(r >> 16);
}
__device__ __forceinline__ float bf2f(short s) {
    union { unsigned u; float f; } v; v.u = ((unsigned)(unsigned short)s) << 16;
    return v.f;
}
__device__ __forceinline__ float sigm(float x) { return 1.0f / (1.0f + expf(-x)); }

// ---------------- prep_all: prep1 + prep2 + pack_w (proven merged kernel, unchanged) ----------------
__global__ __launch_bounds__(256) void prep_all(
    const int* __restrict__ ip, const float* __restrict__ src,
    const float* __restrict__ Aa, const float* __restrict__ sv,
    const float* __restrict__ enc,
    const float* __restrict__ Wfg, const float* __restrict__ Wig,
    const float* __restrict__ Wogb, const float* __restrict__ WogA,
    const float* __restrict__ Wctb,
    short* __restrict__ X1, short* __restrict__ X2,
    short* __restrict__ W1, short* __restrict__ Wog, short* __restrict__ Wct,
    float* __restrict__ pcpt, float* __restrict__ wtail)
{
    const int tid  = threadIdx.x;
    const int t    = blockIdx.x * 256 + tid;      // 0..262143
    const int wid  = t >> 6;                      // 0..4095
    const int lane = tid & 63;
    const int i    = *ip;

    // --- section 1: cosine sims + X2=[Bv|A] bf16, one row per wave ---
    {
        const int b = wid;
        const float* Arow = Aa + (size_t)b * ND;
        const float* Brow = src + ((size_t)b * NS + i) * ND;
        const float* Srow = sv + (size_t)b * ND;
        short* x2row = X2 + (size_t)b * 1024;

        float dab = 0.f, daa = 0.f, dbb = 0.f, das = 0.f, dss = 0.f;
        #pragma unroll
        for (int c = 0; c < 2; ++c) {
            const int d0 = c * 256 + lane * 4;
            f32x4 a  = *(const f32x4*)(Arow + d0);
            f32x4 bv = *(const f32x4*)(Brow + d0);
            f32x4 s  = *(const f32x4*)(Srow + d0);
            #pragma unroll
            for (int j = 0; j < 4; ++j) {
                dab += a[j] * bv[j];
                daa += a[j] * a[j];
                dbb += bv[j] * bv[j];
                das += a[j] * s[j];
                dss += s[j] * s[j];
            }
            short4 qb, qa;
            qb.x = f2bf(bv[0]); qb.y = f2bf(bv[1]); qb.z = f2bf(bv[2]); qb.w = f2bf(bv[3]);
            qa.x = f2bf(a[0]);  qa.y = f2bf(a[1]);  qa.z = f2bf(a[2]);  qa.w = f2bf(a[3]);
            *(short4*)(x2row + d0) = qb;
            *(short4*)(x2row + 512 + d0) = qa;
        }
        #pragma unroll
        for (int off = 32; off; off >>= 1) {
            dab += __shfl_xor(dab, off);
            daa += __shfl_xor(daa, off);
            dbb += __shfl_xor(dbb, off);
            das += __shfl_xor(das, off);
            dss += __shfl_xor(dss, off);
        }
        if (lane == 0) {
            const float na = fmaxf(sqrtf(daa), EPSV);
            const float nb = fmaxf(sqrtf(dbb), EPSV);
            const float ns = fmaxf(sqrtf(dss), EPSV);
            pcpt[b * 2]     = dab / (na * nb);
            pcpt[b * 2 + 1] = das / (na * ns);
        }
    }
    // --- section 2: enc slice -> X1 bf16, 4 float4 per thread ---
    {
        const float* encs = enc + (size_t)i * NB * 1024;
        #pragma unroll
        for (int c = 0; c < 4; ++c) {
            const size_t e4 = (size_t)c * 262144 + t;
            f32x4 v = *(const f32x4*)(encs + e4 * 4);
            short4 q;
            q.x = f2bf(v[0]); q.y = f2bf(v[1]); q.z = f2bf(v[2]); q.w = f2bf(v[3]);
            *(short4*)(X1 + e4 * 4) = q;
        }
    }
    // --- section 3: pack weights, grid-stride over 1,837,056 elems ---
    #pragma unroll 1
    for (int idx = t; idx < 1837056; idx += 262144) {
        if (idx < 1048576) {
            const int n = idx >> 10, k = idx & 1023;
            const float v = (n < 512) ? Wfg[(size_t)n * 1026 + k] : Wig[(size_t)(n - 512) * 1026 + k];
            W1[idx] = f2bf(v);
        } else if (idx < 1572864) {
            const int j = idx - 1048576;
            const int n = j >> 10, k = j & 1023;
            const float v = (k < 512) ? Wogb[(size_t)n * 512 + k] : WogA[(size_t)n * 512 + (k - 512)];
            Wog[j] = f2bf(v);
        } else if (idx < 1835008) {
            const int j = idx - 1572864;
            Wct[j] = f2bf(Wctb[j]);
        } else {
            const int tt = idx - 1835008;           // [0,2048)
            const int r = tt >> 9, d = tt & 511;    // 0=fg/pc 1=fg/pt 2=ig/pc 3=ig/pt
            const float v = (r < 2) ? Wfg[(size_t)d * 1026 + 1024 + r]
                                    : Wig[(size_t)d * 1026 + 1024 + (r - 2)];
            wtail[tt] = v;
        }
    }
}

// ---------------- gemm+finish fused: R11 GEMM body + counter-gated finish ----------------
// GEMM: 64x128 tiles, single-buffer 2-barrier (R11 proven, 843 TF), T2 swizzle both-sides.
// Finish: panel p (64 G-rows) is complete when 16 tiles (8 fi + 4 og + 4 ct, all bx=p) signal
// cnt[p]. Block h then finishes rows [4h,4h+4) in panel h>>4. All 1024 blocks co-resident
// (24KB LDS, <=128 VGPR -> 4 blk/CU) => producers always progress; R6-proven fence pattern.
__global__ __launch_bounds__(256, 4) void gemm_finish(
    const short* __restrict__ X1v, const short* __restrict__ W1v,
    const short* __restrict__ X2v, const short* __restrict__ Wogv,
    const short* __restrict__ Wctv,
    short* __restrict__ Gfi, short* __restrict__ Gog, short* __restrict__ Gct,
    unsigned* __restrict__ cnt,
    const float* __restrict__ pcpt, const float* __restrict__ wtail,
    const float* __restrict__ bfg, const float* __restrict__ big,
    const float* __restrict__ bogb, const float* __restrict__ bogA,
    const float* __restrict__ bctb,
    const float* __restrict__ fw, const float* __restrict__ fb,
    float* __restrict__ out)
{
    __shared__ __align__(16) short As[64 * 64];    //  8 KB
    __shared__ __align__(16) short Bs[128 * 64];   // 16 KB

    const int h = blockIdx.x;
    const int x = h & 7, q = h >> 3;
    const short *Xp, *Wp;
    short* Gp;
    int bx, by, wss, gs, nkt;
    if (q < 64)      { bx = x * 8 + (q >> 3);              by = q & 7;        Xp = X1v; Wp = W1v;  Gp = Gfi; wss = 1024; gs = 1024; nkt = 16; }
    else if (q < 96) { const int j = q - 64; bx = x * 8 + (j >> 2); by = j & 3; Xp = X2v; Wp = Wogv; Gp = Gog; wss = 1024; gs = 512;  nkt = 16; }
    else             { const int j = q - 96; bx = x * 8 + (j >> 2); by = j & 3; Xp = X2v; Wp = Wctv; Gp = Gct; wss = 512;  gs = 512;  nkt = 8;  }

    const int tid = threadIdx.x;
    const int w = tid >> 6, lane = tid & 63;
    const int wm = w >> 1, wn = w & 1;
    const int lr = lane & 15, lg = lane >> 4;
    const int swz = (lr & 7) << 4;       // read-side XOR, row ≡ lr (mod 8)

    const size_t ldx = 2048;             // X row stride bytes (1024 bf16)
    const size_t ldw = (size_t)wss * 2;  // W row stride bytes
    const char* Xb = (const char*)Xp + (size_t)bx * 64 * ldx;
    const char* Wb = (const char*)Wp + (size_t)by * 128 * ldw;

    f32x4 acc[2][4];
    #pragma unroll
    for (int mi = 0; mi < 2; ++mi)
        #pragma unroll
        for (int ni = 0; ni < 4; ++ni)
            acc[mi][ni] = f32x4{0.f, 0.f, 0.f, 0.f};

    for (int kt = 0; kt < nkt; ++kt) {
        __syncthreads();
        #pragma unroll
        for (int s = 0; s < 2; ++s) {
            const int seg = (s * 4 + w) * 1024;
            const int linear = seg + lane * 16;
            const int row = linear >> 7;
            const int kbs = (linear & 127) ^ ((row & 7) << 4);   // pre-swizzled source col
            __builtin_amdgcn_global_load_lds(
                (const __attribute__((address_space(1))) void*)(Xb + (size_t)row * ldx + (size_t)kt * 128 + kbs),
                (__attribute__((address_space(3))) void*)((char*)As + seg),
                16, 0, 0);
        }
        #pragma unroll
        for (int s = 0; s < 4; ++s) {
            const int seg = (s * 4 + w) * 1024;
            const int linear = seg + lane * 16;
            const int row = linear >> 7;
            const int kbs = (linear & 127) ^ ((row & 7) << 4);
            __builtin_amdgcn_global_load_lds(
                (const __attribute__((address_space(1))) void*)(Wb + (size_t)row * ldw + (size_t)kt * 128 + kbs),
                (__attribute__((address_space(3))) void*)((char*)Bs + seg),
                16, 0, 0);
        }
        __syncthreads();
        #pragma unroll
        for (int ks = 0; ks < 2; ++ks) {
            bf16x8 af[2], bfr[4];
            #pragma unroll
            for (int mi = 0; mi < 2; ++mi)
                af[mi] = *(const bf16x8*)((const char*)As + (wm * 32 + mi * 16 + lr) * 128 + ((ks * 64 + lg * 16) ^ swz));
            #pragma unroll
            for (int ni = 0; ni < 4; ++ni)
                bfr[ni] = *(const bf16x8*)((const char*)Bs + (wn * 64 + ni * 16 + lr) * 128 + ((ks * 64 + lg * 16) ^ swz));
            #pragma unroll
            for (int mi = 0; mi < 2; ++mi)
                #pragma unroll
                for (int ni = 0; ni < 4; ++ni)
                    acc[mi][ni] = __builtin_amdgcn_mfma_f32_16x16x32_bf16(af[mi], bfr[ni], acc[mi][ni], 0, 0, 0);
        }
    }

    // epilogue: C/D layout col=lane&15, row=(lane>>4)*4+reg (m89/m91)
    short* Grow = Gp + ((size_t)bx * 64 + wm * 32) * gs + by * 128 + wn * 64;
    #pragma unroll
    for (int mi = 0; mi < 2; ++mi)
        #pragma unroll
        for (int ni = 0; ni < 4; ++ni)
            #pragma unroll
            for (int r = 0; r < 4; ++r)
                Grow[(size_t)(mi * 16 + lg * 4 + r) * gs + ni * 16 + lr] = f2bf(acc[mi][ni][r]);

    // ---- signal: this tile (panel bx) is done ----
    __syncthreads();                       // all waves' G stores issued
    if (tid == 0) {
        __threadfence();                   // release: G visible device-wide
        atomicAdd(&cnt[bx], 1u);           // device-scope (m20)
    }

    // ---- wait: finish-panel h>>4 fully produced (16 tiles) ----
    if (tid == 0) {
        const int fp = h >> 4;
        unsigned iters = 0;
        while (__hip_atomic_load(&cnt[fp], __ATOMIC_RELAXED, __HIP_MEMORY_SCOPE_AGENT) < 16u) {
            __builtin_amdgcn_s_sleep(1);
            if (++iters > 400000000u) break;   // failsafe: never hang
        }
        __threadfence();                   // acquire
    }
    __syncthreads();

    // ---- finish rows [4h, 4h+4): wave w handles row b = 4h + w ----
    {
        const int b = h * 4 + w;
        const int d = lane * 8;
        const float pc = pcpt[b * 2], pt = pcpt[b * 2 + 1];

        bf16x8 vfg = *(const bf16x8*)(Gfi + (size_t)b * 1024 + d);
        bf16x8 vig = *(const bf16x8*)(Gfi + (size_t)b * 1024 + 512 + d);
        bf16x8 vog = *(const bf16x8*)(Gog + (size_t)b * 512 + d);
        bf16x8 vct = *(const bf16x8*)(Gct + (size_t)b * 512 + d);
        bf16x8 vb8 = *(const bf16x8*)(X2v + (size_t)b * 1024 + d);        // Bv
        bf16x8 va8 = *(const bf16x8*)(X2v + (size_t)b * 1024 + 512 + d);  // A

        float hsum = 0.f;
        float av[8], bvv[8];
        #pragma unroll
        for (int c = 0; c < 2; ++c) {
            const int d0 = d + c * 4;
            f32x4 c1 = *(const f32x4*)(bfg + d0);
            f32x4 c2 = *(const f32x4*)(big + d0);
            f32x4 c3 = *(const f32x4*)(bogb + d0);
            f32x4 c4 = *(const f32x4*)(bogA + d0);
            f32x4 c5 = *(const f32x4*)(bctb + d0);
            f32x4 vfw = *(const f32x4*)(fw + d0);
            f32x4 w0 = *(const f32x4*)(wtail + d0);
            f32x4 w1 = *(const f32x4*)(wtail + 512 + d0);
            f32x4 w2 = *(const f32x4*)(wtail + 1024 + d0);
            f32x4 w3 = *(const f32x4*)(wtail + 1536 + d0);
            #pragma unroll
            for (int j = 0; j < 4; ++j) {
                const int e = c * 4 + j;
                const float a  = bf2f(va8[e]);
                const float bv = bf2f(vb8[e]);
                const float fg = sigm(bf2f(vfg[e]) + c1[j] + pc * w0[j] + pt * w1[j]);
                const float ig = sigm(bf2f(vig[e]) + c2[j] + pc * w2[j] + pt * w3[j]);
                const float og = sigm(bf2f(vog[e]) + c3[j] + c4[j]);
                const float ct = fg * a + ig * tanhf(bf2f(vct[e]) + c5[j]);
                const float ht = og * sigm(ct);
                hsum += ht * vfw[j];
                av[e] = a; bvv[e] = bv;
            }
        }
        #pragma unroll
        for (int off = 32; off; off >>= 1) hsum += __shfl_xor(hsum, off);
        const float score = sigm(hsum + fb[0]);
        #pragma unroll
        for (int c = 0; c < 2; ++c) {
            f32x4 o;
            #pragma unroll
            for (int j = 0; j < 4; ++j) {
                const float a = av[c * 4 + j];
                o[j] = a - (a - bvv[c * 4 + j]) * score;
            }
            *(f32x4*)(out + (size_t)b * ND + d + c * 4) = o;
        }
        if (lane == 0) out[(size_t)NB * ND + b] = score;
    }
}

extern "C" void kernel_launch(void* const* d_in, const int* in_sizes, int n_in,
                              void* d_out, int out_size, void* d_ws, size_t ws_size,
                              hipStream_t stream) {
    const int*   ip    = (const int*)d_in[0];
    const float* src   = (const float*)d_in[1];
    const float* enc   = (const float*)d_in[2];
    const float* prev  = (const float*)d_in[3];
    const float* sv    = (const float*)d_in[4];
    const float* Wfg_w = (const float*)d_in[5];
    const float* Wfg_b = (const float*)d_in[6];
    const float* Wig_w = (const float*)d_in[7];
    const float* Wig_b = (const float*)d_in[8];
    const float* Wogb_w = (const float*)d_in[9];
    const float* Wogb_b = (const float*)d_in[10];
    const float* WogA_w = (const float*)d_in[11];
    const float* WogA_b = (const float*)d_in[12];
    const float* Wctb_w = (const float*)d_in[13];
    const float* Wctb_b = (const float*)d_in[14];
    const float* fw    = (const float*)d_in[15];
    const float* fb    = (const float*)d_in[16];

    char* ws = (char*)d_ws;
    short* X1   = (short*)(ws + 0);          // 8,388,608
    short* X2   = (short*)(ws + 8388608);    // 8,388,608
    short* W1   = (short*)(ws + 16777216);   // 2,097,152
    short* Wog  = (short*)(ws + 18874368);   // 1,048,576
    short* Wct  = (short*)(ws + 19922944);   //   524,288
    short* Gfi  = (short*)(ws + 20447232);   // 8,388,608
    short* Gog  = (short*)(ws + 28835840);   // 4,194,304
    short* Gct  = (short*)(ws + 33030144);   // 4,194,304
    float* pcpt = (float*)(ws + 37224448);   //    32,768
    float* wtail= (float*)(ws + 37257216);   //     8,192
    unsigned* cnt = (unsigned*)(ws + 37265408); //   256  (64 panel counters)

    // zero panel counters each launch (graph-capturable memset node)
    hipMemsetAsync(ws + 37265408, 0, 256, stream);

    prep_all<<<1024, 256, 0, stream>>>(ip, src, prev, sv, enc,
                                       Wfg_w, Wig_w, Wogb_w, WogA_w, Wctb_w,
                                       X1, X2, W1, Wog, Wct, pcpt, wtail);
    gemm_finish<<<1024, 256, 0, stream>>>(X1, W1, X2, Wog, Wct, Gfi, Gog, Gct, cnt,
                                          pcpt, wtail,
                                          Wfg_b, Wig_b, Wogb_b, WogA_b, Wctb_b,
                                          fw, fb, (float*)d_out);
}

// Round 14
// 148.046 us; speedup vs baseline: 1.0250x; 1.0250x over previous
//
#include <hip/hip_runtime.h>
#include <hip/hip_bf16.h>
#include <stdint.h>

#define NB 4096
#define NS 64
#define ND 512
#define EPSV 1e-8f

typedef float f32x4 __attribute__((ext_vector_type(4)));
typedef short bf16x8 __attribute__((ext_vector_type(8)));

__device__ __forceinline__ short f2bf(float f) {
    union { float f; unsigned u; } v; v.f = f;
    unsigned r = v.u + 0x7fffu + ((v.u >> 16) & 1u);
    return (short)(r >> 16);
}
__device__ __forceinline__ float bf2f(short s) {
    union { unsigned u; float f; } v; v.u = ((unsigned)(unsigned short)s) << 16;
    return v.f;
}
__device__ __forceinline__ float sigm(float x) { return 1.0f / (1.0f + expf(-x)); }

// ---------------- prep_all: prep1 + prep2 + pack_w (proven, unchanged from R11) ----------------
__global__ __launch_bounds__(256) void prep_all(
    const int* __restrict__ ip, const float* __restrict__ src,
    const float* __restrict__ Aa, const float* __restrict__ sv,
    const float* __restrict__ enc,
    const float* __restrict__ Wfg, const float* __restrict__ Wig,
    const float* __restrict__ Wogb, const float* __restrict__ WogA,
    const float* __restrict__ Wctb,
    short* __restrict__ X1, short* __restrict__ X2,
    short* __restrict__ W1, short* __restrict__ Wog, short* __restrict__ Wct,
    float* __restrict__ pcpt, float* __restrict__ wtail)
{
    const int tid  = threadIdx.x;
    const int t    = blockIdx.x * 256 + tid;      // 0..262143
    const int wid  = t >> 6;                      // 0..4095
    const int lane = tid & 63;
    const int i    = *ip;

    // --- section 1: cosine sims + X2=[Bv|A] bf16, one row per wave ---
    {
        const int b = wid;
        const float* Arow = Aa + (size_t)b * ND;
        const float* Brow = src + ((size_t)b * NS + i) * ND;
        const float* Srow = sv + (size_t)b * ND;
        short* x2row = X2 + (size_t)b * 1024;

        float dab = 0.f, daa = 0.f, dbb = 0.f, das = 0.f, dss = 0.f;
        #pragma unroll
        for (int c = 0; c < 2; ++c) {
            const int d0 = c * 256 + lane * 4;
            f32x4 a  = *(const f32x4*)(Arow + d0);
            f32x4 bv = *(const f32x4*)(Brow + d0);
            f32x4 s  = *(const f32x4*)(Srow + d0);
            #pragma unroll
            for (int j = 0; j < 4; ++j) {
                dab += a[j] * bv[j];
                daa += a[j] * a[j];
                dbb += bv[j] * bv[j];
                das += a[j] * s[j];
                dss += s[j] * s[j];
            }
            short4 qb, qa;
            qb.x = f2bf(bv[0]); qb.y = f2bf(bv[1]); qb.z = f2bf(bv[2]); qb.w = f2bf(bv[3]);
            qa.x = f2bf(a[0]);  qa.y = f2bf(a[1]);  qa.z = f2bf(a[2]);  qa.w = f2bf(a[3]);
            *(short4*)(x2row + d0) = qb;
            *(short4*)(x2row + 512 + d0) = qa;
        }
        #pragma unroll
        for (int off = 32; off; off >>= 1) {
            dab += __shfl_xor(dab, off);
            daa += __shfl_xor(daa, off);
            dbb += __shfl_xor(dbb, off);
            das += __shfl_xor(das, off);
            dss += __shfl_xor(dss, off);
        }
        if (lane == 0) {
            const float na = fmaxf(sqrtf(daa), EPSV);
            const float nb = fmaxf(sqrtf(dbb), EPSV);
            const float ns = fmaxf(sqrtf(dss), EPSV);
            pcpt[b * 2]     = dab / (na * nb);
            pcpt[b * 2 + 1] = das / (na * ns);
        }
    }
    // --- section 2: enc slice -> X1 bf16, 4 float4 per thread ---
    {
        const float* encs = enc + (size_t)i * NB * 1024;
        #pragma unroll
        for (int c = 0; c < 4; ++c) {
            const size_t e4 = (size_t)c * 262144 + t;
            f32x4 v = *(const f32x4*)(encs + e4 * 4);
            short4 q;
            q.x = f2bf(v[0]); q.y = f2bf(v[1]); q.z = f2bf(v[2]); q.w = f2bf(v[3]);
            *(short4*)(X1 + e4 * 4) = q;
        }
    }
    // --- section 3: pack weights, grid-stride over 1,837,056 elems ---
    #pragma unroll 1
    for (int idx = t; idx < 1837056; idx += 262144) {
        if (idx < 1048576) {
            const int n = idx >> 10, k = idx & 1023;
            const float v = (n < 512) ? Wfg[(size_t)n * 1026 + k] : Wig[(size_t)(n - 512) * 1026 + k];
            W1[idx] = f2bf(v);
        } else if (idx < 1572864) {
            const int j = idx - 1048576;
            const int n = j >> 10, k = j & 1023;
            const float v = (k < 512) ? Wogb[(size_t)n * 512 + k] : WogA[(size_t)n * 512 + (k - 512)];
            Wog[j] = f2bf(v);
        } else if (idx < 1835008) {
            const int j = idx - 1572864;
            Wct[j] = f2bf(Wctb[j]);
        } else {
            const int tt = idx - 1835008;           // [0,2048)
            const int r = tt >> 9, d = tt & 511;    // 0=fg/pc 1=fg/pt 2=ig/pc 3=ig/pt
            const float v = (r < 2) ? Wfg[(size_t)d * 1026 + 1024 + r]
                                    : Wig[(size_t)d * 1026 + 1024 + (r - 2)];
            wtail[tt] = v;
        }
    }
}

// ---------------- gemm_finish: block-level branch, DISJOINT paths ----------------
// blocks [0,1024):  R11 GEMM tile (byte-identical), signal cnt[bx], return. Never waits.
// blocks [1024,2048): finish 4 rows, gated on panel counter (16 producer tiles).
// Producers are dispatched first and fill the full 4-blk/CU capacity (grid waves of 1024);
// consumers enter as producers retire -> finish overlaps the GEMM tail.
__global__ __launch_bounds__(256, 4) void gemm_finish(
    const short* __restrict__ X1v, const short* __restrict__ W1v,
    const short* __restrict__ X2v, const short* __restrict__ Wogv,
    const short* __restrict__ Wctv,
    short* __restrict__ Gfi, short* __restrict__ Gog, short* __restrict__ Gct,
    unsigned* __restrict__ cnt,
    const float* __restrict__ pcpt, const float* __restrict__ wtail,
    const float* __restrict__ bfg, const float* __restrict__ big,
    const float* __restrict__ bogb, const float* __restrict__ bogA,
    const float* __restrict__ bctb,
    const float* __restrict__ fw, const float* __restrict__ fb,
    float* __restrict__ out)
{
    __shared__ __align__(16) short As[64 * 64];    //  8 KB
    __shared__ __align__(16) short Bs[128 * 64];   // 16 KB

    const int tid = threadIdx.x;
    const int w = tid >> 6, lane = tid & 63;

    if (blockIdx.x < 1024) {
        // ================= producer path: R11 GEMM, unchanged =================
        const int h = blockIdx.x;
        const int x = h & 7, q = h >> 3;
        const short *Xp, *Wp;
        short* Gp;
        int bx, by, wss, gs, nkt;
        if (q < 64)      { bx = x * 8 + (q >> 3);              by = q & 7;        Xp = X1v; Wp = W1v;  Gp = Gfi; wss = 1024; gs = 1024; nkt = 16; }
        else if (q < 96) { const int j = q - 64; bx = x * 8 + (j >> 2); by = j & 3; Xp = X2v; Wp = Wogv; Gp = Gog; wss = 1024; gs = 512;  nkt = 16; }
        else             { const int j = q - 96; bx = x * 8 + (j >> 2); by = j & 3; Xp = X2v; Wp = Wctv; Gp = Gct; wss = 512;  gs = 512;  nkt = 8;  }

        const int wm = w >> 1, wn = w & 1;
        const int lr = lane & 15, lg = lane >> 4;
        const int swz = (lr & 7) << 4;       // read-side XOR, row ≡ lr (mod 8)

        const size_t ldx = 2048;             // X row stride bytes (1024 bf16)
        const size_t ldw = (size_t)wss * 2;  // W row stride bytes
        const char* Xb = (const char*)Xp + (size_t)bx * 64 * ldx;
        const char* Wb = (const char*)Wp + (size_t)by * 128 * ldw;

        f32x4 acc[2][4];
        #pragma unroll
        for (int mi = 0; mi < 2; ++mi)
            #pragma unroll
            for (int ni = 0; ni < 4; ++ni)
                acc[mi][ni] = f32x4{0.f, 0.f, 0.f, 0.f};

        for (int kt = 0; kt < nkt; ++kt) {
            __syncthreads();
            #pragma unroll
            for (int s = 0; s < 2; ++s) {
                const int seg = (s * 4 + w) * 1024;
                const int linear = seg + lane * 16;
                const int row = linear >> 7;
                const int kbs = (linear & 127) ^ ((row & 7) << 4);   // pre-swizzled source col
                __builtin_amdgcn_global_load_lds(
                    (const __attribute__((address_space(1))) void*)(Xb + (size_t)row * ldx + (size_t)kt * 128 + kbs),
                    (__attribute__((address_space(3))) void*)((char*)As + seg),
                    16, 0, 0);
            }
            #pragma unroll
            for (int s = 0; s < 4; ++s) {
                const int seg = (s * 4 + w) * 1024;
                const int linear = seg + lane * 16;
                const int row = linear >> 7;
                const int kbs = (linear & 127) ^ ((row & 7) << 4);
                __builtin_amdgcn_global_load_lds(
                    (const __attribute__((address_space(1))) void*)(Wb + (size_t)row * ldw + (size_t)kt * 128 + kbs),
                    (__attribute__((address_space(3))) void*)((char*)Bs + seg),
                    16, 0, 0);
            }
            __syncthreads();
            #pragma unroll
            for (int ks = 0; ks < 2; ++ks) {
                bf16x8 af[2], bfr[4];
                #pragma unroll
                for (int mi = 0; mi < 2; ++mi)
                    af[mi] = *(const bf16x8*)((const char*)As + (wm * 32 + mi * 16 + lr) * 128 + ((ks * 64 + lg * 16) ^ swz));
                #pragma unroll
                for (int ni = 0; ni < 4; ++ni)
                    bfr[ni] = *(const bf16x8*)((const char*)Bs + (wn * 64 + ni * 16 + lr) * 128 + ((ks * 64 + lg * 16) ^ swz));
                #pragma unroll
                for (int mi = 0; mi < 2; ++mi)
                    #pragma unroll
                    for (int ni = 0; ni < 4; ++ni)
                        acc[mi][ni] = __builtin_amdgcn_mfma_f32_16x16x32_bf16(af[mi], bfr[ni], acc[mi][ni], 0, 0, 0);
            }
        }

        short* Grow = Gp + ((size_t)bx * 64 + wm * 32) * gs + by * 128 + wn * 64;
        #pragma unroll
        for (int mi = 0; mi < 2; ++mi)
            #pragma unroll
            for (int ni = 0; ni < 4; ++ni)
                #pragma unroll
                for (int r = 0; r < 4; ++r)
                    Grow[(size_t)(mi * 16 + lg * 4 + r) * gs + ni * 16 + lr] = f2bf(acc[mi][ni][r]);

        __syncthreads();                       // all waves' G stores issued
        if (tid == 0) {
            __threadfence();                   // release: G visible device-wide
            atomicAdd(&cnt[bx], 1u);           // device-scope (m20)
        }
        return;                                // producer never waits
    }

    // ================= consumer path: finish 4 rows, counter-gated =================
    {
        const int f = blockIdx.x - 1024;       // 0..1023
        const int panel = f >> 4;              // 64 rows per panel, 16 finish blocks/panel
        if (tid == 0) {
            unsigned long long iters = 0;
            while (__hip_atomic_load(&cnt[panel], __ATOMIC_RELAXED, __HIP_MEMORY_SCOPE_AGENT) < 16u) {
                __builtin_amdgcn_s_sleep(8);
                if (++iters > 4000000000ull) break;   // ~seconds: inversion shows as timeout, not silent corruption
            }
            __threadfence();                   // acquire
        }
        __syncthreads();

        const int b = f * 4 + w;
        const int d = lane * 8;
        const float pc = pcpt[b * 2], pt = pcpt[b * 2 + 1];

        bf16x8 vfg = *(const bf16x8*)(Gfi + (size_t)b * 1024 + d);
        bf16x8 vig = *(const bf16x8*)(Gfi + (size_t)b * 1024 + 512 + d);
        bf16x8 vog = *(const bf16x8*)(Gog + (size_t)b * 512 + d);
        bf16x8 vct = *(const bf16x8*)(Gct + (size_t)b * 512 + d);
        bf16x8 vb8 = *(const bf16x8*)(X2v + (size_t)b * 1024 + d);        // Bv
        bf16x8 va8 = *(const bf16x8*)(X2v + (size_t)b * 1024 + 512 + d);  // A

        float hsum = 0.f;
        float av[8], bvv[8];
        #pragma unroll
        for (int c = 0; c < 2; ++c) {
            const int d0 = d + c * 4;
            f32x4 c1 = *(const f32x4*)(bfg + d0);
            f32x4 c2 = *(const f32x4*)(big + d0);
            f32x4 c3 = *(const f32x4*)(bogb + d0);
            f32x4 c4 = *(const f32x4*)(bogA + d0);
            f32x4 c5 = *(const f32x4*)(bctb + d0);
            f32x4 vfw = *(const f32x4*)(fw + d0);
            f32x4 w0 = *(const f32x4*)(wtail + d0);
            f32x4 w1 = *(const f32x4*)(wtail + 512 + d0);
            f32x4 w2 = *(const f32x4*)(wtail + 1024 + d0);
            f32x4 w3 = *(const f32x4*)(wtail + 1536 + d0);
            #pragma unroll
            for (int j = 0; j < 4; ++j) {
                const int e = c * 4 + j;
                const float a  = bf2f(va8[e]);
                const float bv = bf2f(vb8[e]);
                const float fg = sigm(bf2f(vfg[e]) + c1[j] + pc * w0[j] + pt * w1[j]);
                const float ig = sigm(bf2f(vig[e]) + c2[j] + pc * w2[j] + pt * w3[j]);
                const float og = sigm(bf2f(vog[e]) + c3[j] + c4[j]);
                const float ct = fg * a + ig * tanhf(bf2f(vct[e]) + c5[j]);
                const float ht = og * sigm(ct);
                hsum += ht * vfw[j];
                av[e] = a; bvv[e] = bv;
            }
        }
        #pragma unroll
        for (int off = 32; off; off >>= 1) hsum += __shfl_xor(hsum, off);
        const float score = sigm(hsum + fb[0]);
        #pragma unroll
        for (int c = 0; c < 2; ++c) {
            f32x4 o;
            #pragma unroll
            for (int j = 0; j < 4; ++j) {
                const float a = av[c * 4 + j];
                o[j] = a - (a - bvv[c * 4 + j]) * score;
            }
            *(f32x4*)(out + (size_t)b * ND + d + c * 4) = o;
        }
        if (lane == 0) out[(size_t)NB * ND + b] = score;
    }
}

extern "C" void kernel_launch(void* const* d_in, const int* in_sizes, int n_in,
                              void* d_out, int out_size, void* d_ws, size_t ws_size,
                              hipStream_t stream) {
    const int*   ip    = (const int*)d_in[0];
    const float* src   = (const float*)d_in[1];
    const float* enc   = (const float*)d_in[2];
    const float* prev  = (const float*)d_in[3];
    const float* sv    = (const float*)d_in[4];
    const float* Wfg_w = (const float*)d_in[5];
    const float* Wfg_b = (const float*)d_in[6];
    const float* Wig_w = (const float*)d_in[7];
    const float* Wig_b = (const float*)d_in[8];
    const float* Wogb_w = (const float*)d_in[9];
    const float* Wogb_b = (const float*)d_in[10];
    const float* WogA_w = (const float*)d_in[11];
    const float* WogA_b = (const float*)d_in[12];
    const float* Wctb_w = (const float*)d_in[13];
    const float* Wctb_b = (const float*)d_in[14];
    const float* fw    = (const float*)d_in[15];
    const float* fb    = (const float*)d_in[16];

    char* ws = (char*)d_ws;
    short* X1   = (short*)(ws + 0);          // 8,388,608
    short* X2   = (short*)(ws + 8388608);    // 8,388,608
    short* W1   = (short*)(ws + 16777216);   // 2,097,152
    short* Wog  = (short*)(ws + 18874368);   // 1,048,576
    short* Wct  = (short*)(ws + 19922944);   //   524,288
    short* Gfi  = (short*)(ws + 20447232);   // 8,388,608
    short* Gog  = (short*)(ws + 28835840);   // 4,194,304
    short* Gct  = (short*)(ws + 33030144);   // 4,194,304
    float* pcpt = (float*)(ws + 37224448);   //    32,768
    float* wtail= (float*)(ws + 37257216);   //     8,192
    unsigned* cnt = (unsigned*)(ws + 37265408); //   256  (64 panel counters)

    // zero panel counters each launch (graph-capturable memset node)
    hipMemsetAsync(ws + 37265408, 0, 256, stream);

    prep_all<<<1024, 256, 0, stream>>>(ip, src, prev, sv, enc,
                                       Wfg_w, Wig_w, Wogb_w, WogA_w, Wctb_w,
                                       X1, X2, W1, Wog, Wct, pcpt, wtail);
    gemm_finish<<<2048, 256, 0, stream>>>(X1, W1, X2, Wog, Wct, Gfi, Gog, Gct, cnt,
                                          pcpt, wtail,
                                          Wfg_b, Wig_b, Wogb_b, WogA_b, Wctb_b,
                                          fw, fb, (float*)d_out);
}

// Round 15
// 50.368 us; speedup vs baseline: 3.0127x; 2.9393x over previous
//
#include <hip/hip_runtime.h>
#include <hip/hip_bf16.h>
#include <stdint.h>

#define NB 4096
#define NS 64
#define ND 512
#define EPSV 1e-8f

typedef float f32x4 __attribute__((ext_vector_type(4)));
typedef short bf16x8 __attribute__((ext_vector_type(8)));

__device__ __forceinline__ short f2bf(float f) {
    union { float f; unsigned u; } v; v.f = f;
    unsigned r = v.u + 0x7fffu + ((v.u >> 16) & 1u);
    return (short)(r >> 16);
}
__device__ __forceinline__ float bf2f(short s) {
    union { unsigned u; float f; } v; v.u = ((unsigned)(unsigned short)s) << 16;
    return v.f;
}
__device__ __forceinline__ float sigm(float x) { return 1.0f / (1.0f + expf(-x)); }

// ---------------- prep_all: prep1 + prep2 + pack_w ----------------
__global__ __launch_bounds__(256) void prep_all(
    const int* __restrict__ ip, const float* __restrict__ src,
    const float* __restrict__ Aa, const float* __restrict__ sv,
    const float* __restrict__ enc,
    const float* __restrict__ Wfg, const float* __restrict__ Wig,
    const float* __restrict__ Wogb, const float* __restrict__ WogA,
    const float* __restrict__ Wctb,
    short* __restrict__ X1, short* __restrict__ X2,
    short* __restrict__ W1, short* __restrict__ Wog, short* __restrict__ Wct,
    float* __restrict__ pcpt, float* __restrict__ wtail)
{
    const int tid  = threadIdx.x;
    const int t    = blockIdx.x * 256 + tid;      // 0..262143
    const int wid  = t >> 6;                      // 0..4095
    const int lane = tid & 63;
    const int i    = *ip;

    // --- section 1: cosine sims + X2=[Bv|A] bf16, one row per wave ---
    {
        const int b = wid;
        const float* Arow = Aa + (size_t)b * ND;
        const float* Brow = src + ((size_t)b * NS + i) * ND;
        const float* Srow = sv + (size_t)b * ND;
        short* x2row = X2 + (size_t)b * 1024;

        float dab = 0.f, daa = 0.f, dbb = 0.f, das = 0.f, dss = 0.f;
        #pragma unroll
        for (int c = 0; c < 2; ++c) {
            const int d0 = c * 256 + lane * 4;
            f32x4 a  = *(const f32x4*)(Arow + d0);
            f32x4 bv = *(const f32x4*)(Brow + d0);
            f32x4 s  = *(const f32x4*)(Srow + d0);
            #pragma unroll
            for (int j = 0; j < 4; ++j) {
                dab += a[j] * bv[j];
                daa += a[j] * a[j];
                dbb += bv[j] * bv[j];
                das += a[j] * s[j];
                dss += s[j] * s[j];
            }
            short4 qb, qa;
            qb.x = f2bf(bv[0]); qb.y = f2bf(bv[1]); qb.z = f2bf(bv[2]); qb.w = f2bf(bv[3]);
            qa.x = f2bf(a[0]);  qa.y = f2bf(a[1]);  qa.z = f2bf(a[2]);  qa.w = f2bf(a[3]);
            *(short4*)(x2row + d0) = qb;
            *(short4*)(x2row + 512 + d0) = qa;
        }
        #pragma unroll
        for (int off = 32; off; off >>= 1) {
            dab += __shfl_xor(dab, off);
            daa += __shfl_xor(daa, off);
            dbb += __shfl_xor(dbb, off);
            das += __shfl_xor(das, off);
            dss += __shfl_xor(dss, off);
        }
        if (lane == 0) {
            const float na = fmaxf(sqrtf(daa), EPSV);
            const float nb = fmaxf(sqrtf(dbb), EPSV);
            const float ns = fmaxf(sqrtf(dss), EPSV);
            pcpt[b * 2]     = dab / (na * nb);
            pcpt[b * 2 + 1] = das / (na * ns);
        }
    }
    // --- section 2: enc slice -> X1 bf16, 4 float4 per thread ---
    {
        const float* encs = enc + (size_t)i * NB * 1024;
        #pragma unroll
        for (int c = 0; c < 4; ++c) {
            const size_t e4 = (size_t)c * 262144 + t;
            f32x4 v = *(const f32x4*)(encs + e4 * 4);
            short4 q;
            q.x = f2bf(v[0]); q.y = f2bf(v[1]); q.z = f2bf(v[2]); q.w = f2bf(v[3]);
            *(short4*)(X1 + e4 * 4) = q;
        }
    }
    // --- section 3: pack weights, grid-stride over 1,837,056 elems ---
    #pragma unroll 1
    for (int idx = t; idx < 1837056; idx += 262144) {
        if (idx < 1048576) {
            const int n = idx >> 10, k = idx & 1023;
            const float v = (n < 512) ? Wfg[(size_t)n * 1026 + k] : Wig[(size_t)(n - 512) * 1026 + k];
            W1[idx] = f2bf(v);
        } else if (idx < 1572864) {
            const int j = idx - 1048576;
            const int n = j >> 10, k = j & 1023;
            const float v = (k < 512) ? Wogb[(size_t)n * 512 + k] : WogA[(size_t)n * 512 + (k - 512)];
            Wog[j] = f2bf(v);
        } else if (idx < 1835008) {
            const int j = idx - 1572864;
            Wct[j] = f2bf(Wctb[j]);
        } else {
            const int tt = idx - 1835008;           // [0,2048)
            const int r = tt >> 9, d = tt & 511;    // 0=fg/pc 1=fg/pt 2=ig/pc 3=ig/pt
            const float v = (r < 2) ? Wfg[(size_t)d * 1026 + 1024 + r]
                                    : Wig[(size_t)d * 1026 + 1024 + (r - 2)];
            wtail[tt] = v;
        }
    }
}

// ---------------- gemm: 64x128 tiles, 4/CU, XCD-affinity + T2 XOR-swizzle (R11 proven) ----------------
// LDS layout: physical[row][kb] = logical[row][kb ^ ((row&7)<<4)] (bytes, 16B granular).
// Achieved via pre-swizzled GLOBAL source (linear gload_lds dest, rule #21 form c / m173);
// reads apply the same XOR. Data and FLOP order bit-identical -> absmax unchanged.
__global__ __launch_bounds__(256, 4) void gemm_bt(
    const short* __restrict__ X1v, const short* __restrict__ W1v,
    const short* __restrict__ X2v, const short* __restrict__ Wogv,
    const short* __restrict__ Wctv,
    short* __restrict__ Gfi, short* __restrict__ Gog, short* __restrict__ Gct)
{
    __shared__ __align__(16) short As[64 * 64];    //  8 KB
    __shared__ __align__(16) short Bs[128 * 64];   // 16 KB

    const int h = blockIdx.x;
    const int x = h & 7, q = h >> 3;
    const short *Xp, *Wp;
    short* Gp;
    int bx, by, wss, gs, nkt;
    if (q < 64)      { bx = x * 8 + (q >> 3);              by = q & 7;        Xp = X1v; Wp = W1v;  Gp = Gfi; wss = 1024; gs = 1024; nkt = 16; }
    else if (q < 96) { const int j = q - 64; bx = x * 8 + (j >> 2); by = j & 3; Xp = X2v; Wp = Wogv; Gp = Gog; wss = 1024; gs = 512;  nkt = 16; }
    else             { const int j = q - 96; bx = x * 8 + (j >> 2); by = j & 3; Xp = X2v; Wp = Wctv; Gp = Gct; wss = 512;  gs = 512;  nkt = 8;  }

    const int tid = threadIdx.x;
    const int w = tid >> 6, lane = tid & 63;
    const int wm = w >> 1, wn = w & 1;
    const int lr = lane & 15, lg = lane >> 4;
    const int swz = (lr & 7) << 4;       // read-side XOR, row ≡ lr (mod 8)

    const size_t ldx = 2048;             // X row stride bytes (1024 bf16)
    const size_t ldw = (size_t)wss * 2;  // W row stride bytes
    const char* Xb = (const char*)Xp + (size_t)bx * 64 * ldx;
    const char* Wb = (const char*)Wp + (size_t)by * 128 * ldw;

    f32x4 acc[2][4];
    #pragma unroll
    for (int mi = 0; mi < 2; ++mi)
        #pragma unroll
        for (int ni = 0; ni < 4; ++ni)
            acc[mi][ni] = f32x4{0.f, 0.f, 0.f, 0.f};

    for (int kt = 0; kt < nkt; ++kt) {
        __syncthreads();
        // stage A tile: 64 rows x 128B; source column pre-swizzled
        #pragma unroll
        for (int s = 0; s < 2; ++s) {
            const int seg = (s * 4 + w) * 1024;
            const int linear = seg + lane * 16;
            const int row = linear >> 7;
            const int kbs = (linear & 127) ^ ((row & 7) << 4);   // pre-swizzled source col
            __builtin_amdgcn_global_load_lds(
                (const __attribute__((address_space(1))) void*)(Xb + (size_t)row * ldx + (size_t)kt * 128 + kbs),
                (__attribute__((address_space(3))) void*)((char*)As + seg),
                16, 0, 0);
        }
        // stage B tile: 128 rows x 128B; source column pre-swizzled
        #pragma unroll
        for (int s = 0; s < 4; ++s) {
            const int seg = (s * 4 + w) * 1024;
            const int linear = seg + lane * 16;
            const int row = linear >> 7;
            const int kbs = (linear & 127) ^ ((row & 7) << 4);
            __builtin_amdgcn_global_load_lds(
                (const __attribute__((address_space(1))) void*)(Wb + (size_t)row * ldw + (size_t)kt * 128 + kbs),
                (__attribute__((address_space(3))) void*)((char*)Bs + seg),
                16, 0, 0);
        }
        __syncthreads();
        #pragma unroll
        for (int ks = 0; ks < 2; ++ks) {
            bf16x8 af[2], bfr[4];
            #pragma unroll
            for (int mi = 0; mi < 2; ++mi)
                af[mi] = *(const bf16x8*)((const char*)As + (wm * 32 + mi * 16 + lr) * 128 + ((ks * 64 + lg * 16) ^ swz));
            #pragma unroll
            for (int ni = 0; ni < 4; ++ni)
                bfr[ni] = *(const bf16x8*)((const char*)Bs + (wn * 64 + ni * 16 + lr) * 128 + ((ks * 64 + lg * 16) ^ swz));
            #pragma unroll
            for (int mi = 0; mi < 2; ++mi)
                #pragma unroll
                for (int ni = 0; ni < 4; ++ni)
                    acc[mi][ni] = __builtin_amdgcn_mfma_f32_16x16x32_bf16(af[mi], bfr[ni], acc[mi][ni], 0, 0, 0);
        }
    }

    // C/D layout: col=lane&15, row=(lane>>4)*4+reg (m89/m91)
    short* Grow = Gp + ((size_t)bx * 64 + wm * 32) * gs + by * 128 + wn * 64;
    #pragma unroll
    for (int mi = 0; mi < 2; ++mi)
        #pragma unroll
        for (int ni = 0; ni < 4; ++ni)
            #pragma unroll
            for (int r = 0; r < 4; ++r)
                Grow[(size_t)(mi * 16 + lg * 4 + r) * gs + ni * 16 + lr] = f2bf(acc[mi][ni][r]);
}

// ---------------- finish: gates + rank-2 tail + score + out (A/Bv from bf16 X2) ----------------
__global__ __launch_bounds__(256) void finish_k(
    const int* __restrict__ ip, const short* __restrict__ X2,
    const short* __restrict__ Gfi, const short* __restrict__ Gog, const short* __restrict__ Gct,
    const float* __restrict__ pcpt, const float* __restrict__ wtail,
    const float* __restrict__ bfg, const float* __restrict__ big,
    const float* __restrict__ bogb, const float* __restrict__ bogA, const float* __restrict__ bctb,
    const float* __restrict__ fw, const float* __restrict__ fb,
    float* __restrict__ out)
{
    const int w = threadIdx.x >> 6, lane = threadIdx.x & 63;
    const int b = blockIdx.x * 4 + w;
    const int d = lane * 8;
    const float pc = pcpt[b * 2], pt = pcpt[b * 2 + 1];

    bf16x8 vfg = *(const bf16x8*)(Gfi + (size_t)b * 1024 + d);
    bf16x8 vig = *(const bf16x8*)(Gfi + (size_t)b * 1024 + 512 + d);
    bf16x8 vog = *(const bf16x8*)(Gog + (size_t)b * 512 + d);
    bf16x8 vct = *(const bf16x8*)(Gct + (size_t)b * 512 + d);
    bf16x8 vb8 = *(const bf16x8*)(X2 + (size_t)b * 1024 + d);        // Bv
    bf16x8 va8 = *(const bf16x8*)(X2 + (size_t)b * 1024 + 512 + d);  // A

    float hsum = 0.f;
    float av[8], bvv[8];
    #pragma unroll
    for (int c = 0; c < 2; ++c) {
        const int d0 = d + c * 4;
        f32x4 c1 = *(const f32x4*)(bfg + d0);
        f32x4 c2 = *(const f32x4*)(big + d0);
        f32x4 c3 = *(const f32x4*)(bogb + d0);
        f32x4 c4 = *(const f32x4*)(bogA + d0);
        f32x4 c5 = *(const f32x4*)(bctb + d0);
        f32x4 vfw = *(const f32x4*)(fw + d0);
        f32x4 w0 = *(const f32x4*)(wtail + d0);
        f32x4 w1 = *(const f32x4*)(wtail + 512 + d0);
        f32x4 w2 = *(const f32x4*)(wtail + 1024 + d0);
        f32x4 w3 = *(const f32x4*)(wtail + 1536 + d0);
        #pragma unroll
        for (int j = 0; j < 4; ++j) {
            const int e = c * 4 + j;
            const float a  = bf2f(va8[e]);
            const float bv = bf2f(vb8[e]);
            const float fg = sigm(bf2f(vfg[e]) + c1[j] + pc * w0[j] + pt * w1[j]);
            const float ig = sigm(bf2f(vig[e]) + c2[j] + pc * w2[j] + pt * w3[j]);
            const float og = sigm(bf2f(vog[e]) + c3[j] + c4[j]);
            const float ct = fg * a + ig * tanhf(bf2f(vct[e]) + c5[j]);
            const float ht = og * sigm(ct);
            hsum += ht * vfw[j];
            av[e] = a; bvv[e] = bv;
        }
    }
    #pragma unroll
    for (int off = 32; off; off >>= 1) hsum += __shfl_xor(hsum, off);
    const float score = sigm(hsum + fb[0]);
    #pragma unroll
    for (int c = 0; c < 2; ++c) {
        f32x4 o;
        #pragma unroll
        for (int j = 0; j < 4; ++j) {
            const float a = av[c * 4 + j];
            o[j] = a - (a - bvv[c * 4 + j]) * score;
        }
        *(f32x4*)(out + (size_t)b * ND + d + c * 4) = o;
    }
    if (lane == 0) out[(size_t)NB * ND + b] = score;
}

extern "C" void kernel_launch(void* const* d_in, const int* in_sizes, int n_in,
                              void* d_out, int out_size, void* d_ws, size_t ws_size,
                              hipStream_t stream) {
    const int*   ip    = (const int*)d_in[0];
    const float* src   = (const float*)d_in[1];
    const float* enc   = (const float*)d_in[2];
    const float* prev  = (const float*)d_in[3];
    const float* sv    = (const float*)d_in[4];
    const float* Wfg_w = (const float*)d_in[5];
    const float* Wfg_b = (const float*)d_in[6];
    const float* Wig_w = (const float*)d_in[7];
    const float* Wig_b = (const float*)d_in[8];
    const float* Wogb_w = (const float*)d_in[9];
    const float* Wogb_b = (const float*)d_in[10];
    const float* WogA_w = (const float*)d_in[11];
    const float* WogA_b = (const float*)d_in[12];
    const float* Wctb_w = (const float*)d_in[13];
    const float* Wctb_b = (const float*)d_in[14];
    const float* fw    = (const float*)d_in[15];
    const float* fb    = (const float*)d_in[16];

    char* ws = (char*)d_ws;
    short* X1   = (short*)(ws + 0);          // 8,388,608
    short* X2   = (short*)(ws + 8388608);    // 8,388,608
    short* W1   = (short*)(ws + 16777216);   // 2,097,152
    short* Wog  = (short*)(ws + 18874368);   // 1,048,576
    short* Wct  = (short*)(ws + 19922944);   //   524,288
    short* Gfi  = (short*)(ws + 20447232);   // 8,388,608
    short* Gog  = (short*)(ws + 28835840);   // 4,194,304
    short* Gct  = (short*)(ws + 33030144);   // 4,194,304
    float* pcpt = (float*)(ws + 37224448);   //    32,768
    float* wtail= (float*)(ws + 37257216);   //     8,192  ; end 37,265,408

    prep_all<<<1024, 256, 0, stream>>>(ip, src, prev, sv, enc,
                                       Wfg_w, Wig_w, Wogb_w, WogA_w, Wctb_w,
                                       X1, X2, W1, Wog, Wct, pcpt, wtail);
    gemm_bt<<<1024, 256, 0, stream>>>(X1, W1, X2, Wog, Wct, Gfi, Gog, Gct);
    finish_k<<<1024, 256, 0, stream>>>(ip, X2, Gfi, Gog, Gct, pcpt, wtail,
                                       Wfg_b, Wig_b, Wogb_b, WogA_b, Wctb_b,
                                       fw, fb, (float*)d_out);
}